// Round 8
// baseline (157.175 us; speedup 1.0000x reference)
//
#include <hip/hip_runtime.h>
#include <math.h>

#define NE 8
#define PI_F 3.14159265358979323846f

typedef _Float16 half8 __attribute__((ext_vector_type(8)));
typedef float f32x4 __attribute__((ext_vector_type(4)));
typedef unsigned int uint2v __attribute__((ext_vector_type(2)));
typedef unsigned short u16x4 __attribute__((ext_vector_type(4)));

// Activation LDS layout: fp16, [y 0..9][x 0..9][c 0..23(pad)], u16 units
#define CP 24
#define ROWS 240        // 10 * CP
#define NELEM 2400      // 10*10*CP u16

__device__ __forceinline__ unsigned short f2h_bits(float v) {
    union { _Float16 h; unsigned short u; } cv;
    cv.h = (_Float16)v;
    return cv.u;
}

// ---------------- Setup: routers (blocks 0..255) + weight prep (256..575) ---
struct SetupArgs {
    const float* rw[4]; const float* rb[4]; const float* rlw[4]; const float* rlb[4];
    const float* ew[4];
    float* probs;
    unsigned short* w0; unsigned short* w1; unsigned short* w2; unsigned short* w3;
};

template<int CIN, int COUT_R, int COUT_P, int CSTR, int KS>
__device__ __forceinline__ void prep_one(
    const float* __restrict__ ew, unsigned short* __restrict__ wA, int idx)
{
    int j    = idx & 7;
    int lane = (idx >> 3) & 63;
    int t2   = idx >> 9;
    int ks   = t2 % KS;
    int mt   = t2 / KS;
    int m    = mt * 16 + (lane & 15);
    int e    = m / COUT_P, row = m % COUT_P;
    int k    = ks * 32 + (lane >> 4) * 8 + j;
    int cin  = k % CSTR, r = k / CSTR;
    float val = 0.0f;
    if (row < COUT_R && cin < CIN && r < 9)
        val = ew[((size_t)(e * COUT_R + row) * CIN + cin) * 9 + r];
    wA[idx] = f2h_bits(val);
}

__global__ __launch_bounds__(256) void setup_all(SetupArgs sa)
{
    int bx = blockIdx.x, tid = threadIdx.x;
    if (bx < 256) {
        int layer = tid >> 6, lane = tid & 63;
        const float* rw  = sa.rw[layer];  const float* rb  = sa.rb[layer];
        const float* rlw = sa.rlw[layer]; const float* rlb = sa.rlb[layer];
        int p = bx, py = p >> 4, px = p & 15;
        int i = lane >> 3, j = lane & 7;
        int y = py * 8 + i, x = px * 8 + j;

        float base0 = (x + 0.5f) / 128.0f;
        float base1 = (y + 0.5f) / 128.0f;
        float base2 = (j + 0.5f) / 8.0f;
        float base3 = (i + 0.5f) / 8.0f;

        float coord[52];
        coord[0] = base0; coord[1] = base1; coord[2] = base2; coord[3] = base3;
        int c = 4;
        #pragma unroll
        for (int f = 0; f < 6; ++f) {
            float w = PI_F * (float)(1 << f);
            coord[c+0] = sinf(w * base0); coord[c+1] = sinf(w * base1);
            coord[c+2] = sinf(w * base2); coord[c+3] = sinf(w * base3);
            coord[c+4] = cosf(w * base0); coord[c+5] = cosf(w * base1);
            coord[c+6] = cosf(w * base2); coord[c+7] = cosf(w * base3);
            c += 8;
        }
        float z[16];
        #pragma unroll
        for (int r = 0; r < 16; ++r) {
            float a = rb[r];
            #pragma unroll
            for (int cc = 0; cc < 52; ++cc) a += rw[r*52 + cc] * coord[cc];
            z[r] = fmaxf(a, 0.0f);
        }
        #pragma unroll
        for (int r = 0; r < 16; ++r) {
            float v = z[r];
            #pragma unroll
            for (int off = 32; off > 0; off >>= 1) v += __shfl_xor(v, off);
            z[r] = v * (1.0f / 64.0f);
        }
        int e = lane & 7;
        float logit = rlb[e];
        #pragma unroll
        for (int r = 0; r < 16; ++r) logit += rlw[e*16 + r] * z[r];
        float m = logit;
        #pragma unroll
        for (int off = 4; off > 0; off >>= 1) m = fmaxf(m, __shfl_xor(m, off));
        float ex = expf(logit - m);
        float s = ex;
        #pragma unroll
        for (int off = 4; off > 0; off >>= 1) s += __shfl_xor(s, off);
        float pr = ex / s;
        pr = (pr >= 0.05f) ? pr : 0.0f;
        float s2 = pr;
        #pragma unroll
        for (int off = 4; off > 0; off >>= 1) s2 += __shfl_xor(s2, off);
        pr = pr / (s2 + 1e-9f);
        if (lane < 8) sa.probs[layer * 2048 + p * 8 + lane] = pr;
    } else {
        int idx = (bx - 256) * 256 + tid;
        if (idx < 8192)       prep_one<3, 8, 16, 4, 2>(sa.ew[0], sa.w0, idx);
        else if (idx < 20480) prep_one<8, 16, 16, 8, 3>(sa.ew[1], sa.w1, idx - 8192);
        else if (idx < 40960) prep_one<16, 16, 16, 16, 5>(sa.ew[2], sa.w2, idx - 20480);
        else if (idx < 81920) prep_one<16, 32, 32, 16, 5>(sa.ew[3], sa.w3, idx - 40960);
    }
}

// ---------------- One layer inside the fused kernel -------------------------
// Dense compile-time mtile loop: pe=0 experts contribute exactly 0 via the
// fmaf, so no active-list needed. Unroll exposes independent MFMA chains and
// lets the compiler prefetch A-loads across iterations.
template<int KS, int CSTR, int MT, int MPE, bool LAST>
__device__ __forceinline__ void layer_run(
    const unsigned short* ain, unsigned short* aout,
    const unsigned short* __restrict__ wA,
    const float* sbL, const float* seL,
    int l, int lane4, int pr, int pc, int row4, float (*ps)[32], int nt)
{
    const int rbase = pr * ROWS + pc * CP;              // read base (centered)
    const int wbase = (1 + pr) * ROWS + (1 + pc) * CP;  // write base (interior)

    // ---- B fragments: contiguous fp16 ds_reads, no repack ----
    half8 Bh[KS];
    if (CSTR == 16) {
        int cb = (lane4 & 1) * 8;
        int rb = lane4 >> 1;
        #pragma unroll
        for (int ks = 0; ks < KS; ++ks) {
            int r0 = 2 * ks, r1 = 2 * ks + 1;
            int o0 = ((r0 / 3) * 10 + (r0 % 3)) * CP;
            int o1 = ((r1 / 3) * 10 + (r1 % 3)) * CP;
            int off = rb ? o1 : o0;
            half8 v{};
            if (2 * ks + rb < 9) v = *(const half8*)(ain + rbase + off + cb);
            Bh[ks] = v;
        }
    } else if (CSTR == 8) {
        #pragma unroll
        for (int ks = 0; ks < KS; ++ks) {
            int r = 4 * ks + lane4;
            int dy = (r * 11) >> 5, dx = r - 3 * dy;
            int off = (dy * 10 + dx) * CP;
            half8 v{};
            if (r < 9) v = *(const half8*)(ain + rbase + off);
            Bh[ks] = v;
        }
    } else { // CSTR == 4
        #pragma unroll
        for (int ks = 0; ks < KS; ++ks) {
            union { half8 v; uint2v u2[2]; } bb;
            #pragma unroll
            for (int h = 0; h < 2; ++h) {
                int r = 8 * ks + 2 * lane4 + h;
                int dy = (r * 11) >> 5, dx = r - 3 * dy;
                int off = (dy * 10 + dx) * CP;
                uint2v u{};
                if (r < 9) u = *(const uint2v*)(ain + rbase + off);
                bb.u2[h] = u;
            }
            Bh[ks] = bb.v;
        }
    }

    // ---- expert probs preloaded as broadcast vector reads ----
    f32x4 peA = *(const f32x4*)(seL);       // experts 0..3
    f32x4 peB = *(const f32x4*)(seL + 4);   // experts 4..7

    f32x4 acc0 = {0.f, 0.f, 0.f, 0.f};
    f32x4 acc1 = {0.f, 0.f, 0.f, 0.f};
    const unsigned short* apl = wA + l * 8;

    #pragma unroll
    for (int mt = 0; mt < MT; ++mt) {
        const unsigned short* ap = apl + mt * (KS * 512);
        f32x4 ct = *(const f32x4*)&sbL[mt * 16 + row4];   // bias as C-init
        #pragma unroll
        for (int ks = 0; ks < KS; ++ks) {
            half8 a = *(const half8*)(ap + ks * 512);
            ct = __builtin_amdgcn_mfma_f32_16x16x32_f16(a, Bh[ks], ct, 0, 0, 0);
        }
        const int e = (MPE == 2) ? (mt >> 1) : mt;        // compile-time
        float pe = (e < 4) ? peA[e] : peB[e - 4];
        #pragma unroll
        for (int j = 0; j < 4; ++j) {
            float v = fmaxf(ct[j], 0.0f);
            if (MPE == 2 && (mt & 1)) acc1[j] = fmaf(v, pe, acc1[j]);
            else                      acc0[j] = fmaf(v, pe, acc0[j]);
        }
    }

    if (!LAST) {
        union { _Float16 h[4]; u16x4 u; } o;
        #pragma unroll
        for (int j = 0; j < 4; ++j) o.h[j] = (_Float16)acc0[j];
        *(u16x4*)(aout + wbase + row4) = o.u;
    } else {
        #pragma unroll
        for (int j = 0; j < 4; ++j) {
            float s0 = acc0[j], s1 = acc1[j];
            #pragma unroll
            for (int off = 1; off < 16; off <<= 1) {
                s0 += __shfl_xor(s0, off);
                s1 += __shfl_xor(s1, off);
            }
            if ((l & 15) == 0) {
                ps[nt][row4 + j] = s0;
                ps[nt][16 + row4 + j] = s1;
            }
        }
    }
}

// ---------------- Fused all-4-layer conv + per-patch channel sums -----------
__global__ __launch_bounds__(256, 6) void pce_fused(
    const float* __restrict__ X,
    const unsigned short* __restrict__ wA0, const unsigned short* __restrict__ wA1,
    const unsigned short* __restrict__ wA2, const unsigned short* __restrict__ wA3,
    const float* __restrict__ eb0, const float* __restrict__ eb1,
    const float* __restrict__ eb2, const float* __restrict__ eb3,
    const float* __restrict__ probs,  // [4][256][8]
    float* __restrict__ psums)        // [16][256][32]
{
    int bx = blockIdx.x;
    int b = bx >> 8, p = bx & 255;
    int py = p >> 4, px = p & 15;
    int tid = threadIdx.x;

    __shared__ unsigned short A0[NELEM];
    __shared__ unsigned short A1[NELEM];
    __shared__ alignas(16) float sb[640];
    __shared__ alignas(16) float se[4][8];
    __shared__ float ps[4][32];

    for (int t = tid; t < NELEM / 2; t += 256) {
        ((unsigned int*)A0)[t] = 0u;
        ((unsigned int*)A1)[t] = 0u;
    }
    for (int t = tid; t < 192; t += 256) {
        int cin = t >> 6, pix = t & 63, i = pix >> 3, j = pix & 7;
        float v = X[((size_t)(b * 3 + cin) * 128 + (py * 8 + i)) * 128 + (px * 8 + j)];
        A0[(1 + i) * ROWS + (1 + j) * CP + cin] = f2h_bits(v);
    }
    if (tid < 32) se[tid >> 3][tid & 7] = probs[(tid >> 3) * 2048 + p * 8 + (tid & 7)];
    for (int t = tid; t < 640; t += 256) {
        float v;
        if (t < 128)      { int e = t >> 4, r = t & 15; v = (r < 8) ? eb0[e * 8 + r] : 0.0f; }
        else if (t < 256) v = eb1[t - 128];
        else if (t < 384) v = eb2[t - 256];
        else              v = eb3[t - 384];
        sb[t] = v;
    }
    __syncthreads();

    int l = tid & 63, nt = tid >> 6;
    int n = nt * 16 + (l & 15);
    int pr = n >> 3, pc = n & 7;
    int lane4 = l >> 4, row4 = lane4 * 4;

    layer_run<2, 4, 8, 1, false>(A0, A1, wA0, sb,       se[0], l, lane4, pr, pc, row4, nullptr, nt);
    __syncthreads();
    layer_run<3, 8, 8, 1, false>(A1, A0, wA1, sb + 128, se[1], l, lane4, pr, pc, row4, nullptr, nt);
    __syncthreads();
    layer_run<5, 16, 8, 1, false>(A0, A1, wA2, sb + 256, se[2], l, lane4, pr, pc, row4, nullptr, nt);
    __syncthreads();
    layer_run<5, 16, 16, 2, true>(A1, A0, wA3, sb + 384, se[3], l, lane4, pr, pc, row4, ps, nt);
    __syncthreads();

    if (tid < 32) {
        float s = ps[0][tid] + ps[1][tid] + ps[2][tid] + ps[3][tid];
        psums[(size_t)(b * 256 + p) * 32 + tid] = s;
    }
}

// ---------------- FC: 128 blocks = 16 b x 8 class-chunks --------------------
__global__ __launch_bounds__(256) void fc_kernel(
    const float* __restrict__ psums, const float* __restrict__ fcw,
    const float* __restrict__ fcb, float* __restrict__ out)
{
    int b = blockIdx.x >> 3, chunk = blockIdx.x & 7;
    __shared__ float pooled[2048];
    for (int t = threadIdx.x; t < 2048; t += 256) {
        int c = t >> 6, cell = t & 63, oy = cell >> 3, ox = cell & 7;
        float s = 0.0f;
        #pragma unroll
        for (int dy = 0; dy < 2; ++dy)
            #pragma unroll
            for (int dx = 0; dx < 2; ++dx) {
                int pp = (2 * oy + dy) * 16 + (2 * ox + dx);
                s += psums[(size_t)(b * 256 + pp) * 32 + c];
            }
        pooled[t] = s * (1.0f / 256.0f);
    }
    __syncthreads();

    int wave = threadIdx.x >> 6, lane = threadIdx.x & 63;
    for (int ci = wave; ci < 13; ci += 4) {
        int cls = chunk * 13 + ci;
        if (cls < 100) {
            float a = 0.0f;
            #pragma unroll
            for (int r = 0; r < 32; ++r)
                a += pooled[r * 64 + lane] * fcw[(size_t)cls * 2048 + r * 64 + lane];
            #pragma unroll
            for (int off = 32; off > 0; off >>= 1) a += __shfl_down(a, off);
            if (lane == 0) out[b * 100 + cls] = a + fcb[cls];
        }
    }
}

// ---------------- Launch ----------------------------------------------------
extern "C" void kernel_launch(void* const* d_in, const int* in_sizes, int n_in,
                              void* d_out, int out_size, void* d_ws, size_t ws_size,
                              hipStream_t stream) {
    const float* X = (const float*)d_in[0];
    const float* eb[4];
    SetupArgs sa;
    for (int l = 0; l < 4; ++l) {
        sa.ew[l]  = (const float*)d_in[1 + 6*l + 0];
        eb[l]     = (const float*)d_in[1 + 6*l + 1];
        sa.rw[l]  = (const float*)d_in[1 + 6*l + 2];
        sa.rb[l]  = (const float*)d_in[1 + 6*l + 3];
        sa.rlw[l] = (const float*)d_in[1 + 6*l + 4];
        sa.rlb[l] = (const float*)d_in[1 + 6*l + 5];
    }
    const float* fcw = (const float*)d_in[25];
    const float* fcb = (const float*)d_in[26];

    char* ws = (char*)d_ws;
    float* probs  = (float*)ws;                       // 32 KB
    float* psums  = (float*)(ws + 32768);             // 512 KB
    unsigned short* wA0 = (unsigned short*)(ws + 32768 + 524288);
    unsigned short* wA1 = wA0 + 8192;
    unsigned short* wA2 = wA1 + 12288;
    unsigned short* wA3 = wA2 + 20480;                // + 40960

    sa.probs = probs; sa.w0 = wA0; sa.w1 = wA1; sa.w2 = wA2; sa.w3 = wA3;

    setup_all<<<576, 256, 0, stream>>>(sa);
    pce_fused<<<4096, 256, 0, stream>>>(X, wA0, wA1, wA2, wA3,
                                        eb[0], eb[1], eb[2], eb[3], probs, psums);
    fc_kernel<<<128, 256, 0, stream>>>(psums, fcw, fcb, (float*)d_out);
}

// Round 9
// 106.658 us; speedup vs baseline: 1.4736x; 1.4736x over previous
//
#include <hip/hip_runtime.h>
#include <math.h>

#define NE 8
#define PI_F 3.14159265358979323846f

typedef _Float16 half8 __attribute__((ext_vector_type(8)));
typedef float f32x4 __attribute__((ext_vector_type(4)));
typedef unsigned int uint2v __attribute__((ext_vector_type(2)));
typedef unsigned int u32x4 __attribute__((ext_vector_type(4)));
typedef unsigned short u16x4 __attribute__((ext_vector_type(4)));

// Activation LDS layout: fp16, [y 0..9][x 0..9][c 0..23(pad)], u16 units
#define CP 24
#define ROWS 240        // 10 * CP
#define NELEM 2400      // 10*10*CP u16

__device__ __forceinline__ unsigned short f2h_bits(float v) {
    union { _Float16 h; unsigned short u; } cv;
    cv.h = (_Float16)v;
    return cv.u;
}

// ---------------- Setup: routers (blocks 0..255) + weight prep (256..575) ---
struct SetupArgs {
    const float* rw[4]; const float* rb[4]; const float* rlw[4]; const float* rlb[4];
    const float* ew[4];
    float* probs;
    unsigned short* w0; unsigned short* w1; unsigned short* w2; unsigned short* w3;
};

template<int CIN, int COUT_R, int COUT_P, int CSTR, int KS>
__device__ __forceinline__ void prep_one(
    const float* __restrict__ ew, unsigned short* __restrict__ wA, int idx)
{
    int j    = idx & 7;
    int lane = (idx >> 3) & 63;
    int t2   = idx >> 9;
    int ks   = t2 % KS;
    int mt   = t2 / KS;
    int m    = mt * 16 + (lane & 15);
    int e    = m / COUT_P, row = m % COUT_P;
    int k    = ks * 32 + (lane >> 4) * 8 + j;
    int cin  = k % CSTR, r = k / CSTR;
    float val = 0.0f;
    if (row < COUT_R && cin < CIN && r < 9)
        val = ew[((size_t)(e * COUT_R + row) * CIN + cin) * 9 + r];
    wA[idx] = f2h_bits(val);
}

__global__ __launch_bounds__(256) void setup_all(SetupArgs sa)
{
    int bx = blockIdx.x, tid = threadIdx.x;
    if (bx < 256) {
        int layer = tid >> 6, lane = tid & 63;
        const float* rw  = sa.rw[layer];  const float* rb  = sa.rb[layer];
        const float* rlw = sa.rlw[layer]; const float* rlb = sa.rlb[layer];
        int p = bx, py = p >> 4, px = p & 15;
        int i = lane >> 3, j = lane & 7;
        int y = py * 8 + i, x = px * 8 + j;

        float base0 = (x + 0.5f) / 128.0f;
        float base1 = (y + 0.5f) / 128.0f;
        float base2 = (j + 0.5f) / 8.0f;
        float base3 = (i + 0.5f) / 8.0f;

        float coord[52];
        coord[0] = base0; coord[1] = base1; coord[2] = base2; coord[3] = base3;
        int c = 4;
        #pragma unroll
        for (int f = 0; f < 6; ++f) {
            float w = PI_F * (float)(1 << f);
            coord[c+0] = sinf(w * base0); coord[c+1] = sinf(w * base1);
            coord[c+2] = sinf(w * base2); coord[c+3] = sinf(w * base3);
            coord[c+4] = cosf(w * base0); coord[c+5] = cosf(w * base1);
            coord[c+6] = cosf(w * base2); coord[c+7] = cosf(w * base3);
            c += 8;
        }
        float z[16];
        #pragma unroll
        for (int r = 0; r < 16; ++r) {
            float a = rb[r];
            #pragma unroll
            for (int cc = 0; cc < 52; ++cc) a += rw[r*52 + cc] * coord[cc];
            z[r] = fmaxf(a, 0.0f);
        }
        #pragma unroll
        for (int r = 0; r < 16; ++r) {
            float v = z[r];
            #pragma unroll
            for (int off = 32; off > 0; off >>= 1) v += __shfl_xor(v, off);
            z[r] = v * (1.0f / 64.0f);
        }
        int e = lane & 7;
        float logit = rlb[e];
        #pragma unroll
        for (int r = 0; r < 16; ++r) logit += rlw[e*16 + r] * z[r];
        float m = logit;
        #pragma unroll
        for (int off = 4; off > 0; off >>= 1) m = fmaxf(m, __shfl_xor(m, off));
        float ex = expf(logit - m);
        float s = ex;
        #pragma unroll
        for (int off = 4; off > 0; off >>= 1) s += __shfl_xor(s, off);
        float pr = ex / s;
        pr = (pr >= 0.05f) ? pr : 0.0f;
        float s2 = pr;
        #pragma unroll
        for (int off = 4; off > 0; off >>= 1) s2 += __shfl_xor(s2, off);
        pr = pr / (s2 + 1e-9f);
        if (lane < 8) sa.probs[layer * 2048 + p * 8 + lane] = pr;
    } else {
        int idx = (bx - 256) * 256 + tid;
        if (idx < 8192)       prep_one<3, 8, 16, 4, 2>(sa.ew[0], sa.w0, idx);
        else if (idx < 20480) prep_one<8, 16, 16, 8, 3>(sa.ew[1], sa.w1, idx - 8192);
        else if (idx < 40960) prep_one<16, 16, 16, 16, 5>(sa.ew[2], sa.w2, idx - 20480);
        else if (idx < 81920) prep_one<16, 32, 32, 16, 5>(sa.ew[3], sa.w3, idx - 40960);
    }
}

// ---------------- One layer inside the fused kernel -------------------------
// Runtime mtile loop (#pragma unroll 1) with explicit 1-deep A/bias prefetch.
// pe fetched one iteration ahead via __shfl from lane-resident prob register.
template<int KS, int CSTR, int MT, int MPE, bool LAST>
__device__ __forceinline__ void layer_run(
    const unsigned short* ain, unsigned short* aout,
    const unsigned short* __restrict__ wA,
    const float* sbL, const float* seL,
    int l, int lane4, int pr, int pc, int row4, float (*ps)[32], int nt)
{
    const int rbase = pr * ROWS + pc * CP;              // read base (centered)
    const int wbase = (1 + pr) * ROWS + (1 + pc) * CP;  // write base (interior)

    // ---- B fragments: contiguous fp16 ds_reads, no repack ----
    half8 Bh[KS];
    if (CSTR == 16) {
        int cb = (lane4 & 1) * 8;
        int rb = lane4 >> 1;
        #pragma unroll
        for (int ks = 0; ks < KS; ++ks) {
            int r0 = 2 * ks, r1 = 2 * ks + 1;
            int o0 = ((r0 / 3) * 10 + (r0 % 3)) * CP;
            int o1 = ((r1 / 3) * 10 + (r1 % 3)) * CP;
            int off = rb ? o1 : o0;
            half8 v{};
            if (2 * ks + rb < 9) v = *(const half8*)(ain + rbase + off + cb);
            Bh[ks] = v;
        }
    } else if (CSTR == 8) {
        #pragma unroll
        for (int ks = 0; ks < KS; ++ks) {
            int r = 4 * ks + lane4;
            int dy = (r * 11) >> 5, dx = r - 3 * dy;
            int off = (dy * 10 + dx) * CP;
            half8 v{};
            if (r < 9) v = *(const half8*)(ain + rbase + off);
            Bh[ks] = v;
        }
    } else { // CSTR == 4
        #pragma unroll
        for (int ks = 0; ks < KS; ++ks) {
            union { half8 v; uint2v u2[2]; } bb;
            #pragma unroll
            for (int h = 0; h < 2; ++h) {
                int r = 8 * ks + 2 * lane4 + h;
                int dy = (r * 11) >> 5, dx = r - 3 * dy;
                int off = (dy * 10 + dx) * CP;
                uint2v u{};
                if (r < 9) u = *(const uint2v*)(ain + rbase + off);
                bb.u2[h] = u;
            }
            Bh[ks] = bb.v;
        }
    }

    float pev = seL[l & 7];   // lane-resident prob for expert (l&7)

    f32x4 acc0 = {0.f, 0.f, 0.f, 0.f};
    f32x4 acc1 = {0.f, 0.f, 0.f, 0.f};
    const unsigned short* apl = wA + l * 8;

    half8 Acur[KS], Anxt[KS];
    #pragma unroll
    for (int ks = 0; ks < KS; ++ks)
        Acur[ks] = *(const half8*)(apl + ks * 512);
    f32x4 bias = *(const f32x4*)&sbL[row4];
    float pe = __shfl(pev, 0);

    if (MPE == 1) {
        #pragma unroll 1
        for (int mt = 0; mt < MT; ++mt) {
            int mtn = (mt + 1 < MT) ? mt + 1 : 0;
            const unsigned short* apn = apl + mtn * (KS * 512);
            #pragma unroll
            for (int ks = 0; ks < KS; ++ks)
                Anxt[ks] = *(const half8*)(apn + ks * 512);
            f32x4 biasn = *(const f32x4*)&sbL[mtn * 16 + row4];
            float pen = __shfl(pev, mtn);

            f32x4 ct = bias;
            #pragma unroll
            for (int ks = 0; ks < KS; ++ks)
                ct = __builtin_amdgcn_mfma_f32_16x16x32_f16(Acur[ks], Bh[ks], ct, 0, 0, 0);
            #pragma unroll
            for (int j = 0; j < 4; ++j)
                acc0[j] = fmaf(fmaxf(ct[j], 0.0f), pe, acc0[j]);

            #pragma unroll
            for (int ks = 0; ks < KS; ++ks) Acur[ks] = Anxt[ks];
            bias = biasn; pe = pen;
        }
    } else {
        #pragma unroll 1
        for (int ee = 0; ee < 8; ++ee) {
            // sub 0 (rows 0..15 of expert ee) -> acc0 ; prefetch mt=2ee+1
            {
                const unsigned short* apn = apl + (2 * ee + 1) * (KS * 512);
                #pragma unroll
                for (int ks = 0; ks < KS; ++ks)
                    Anxt[ks] = *(const half8*)(apn + ks * 512);
                f32x4 biasn = *(const f32x4*)&sbL[(2 * ee + 1) * 16 + row4];

                f32x4 ct = bias;
                #pragma unroll
                for (int ks = 0; ks < KS; ++ks)
                    ct = __builtin_amdgcn_mfma_f32_16x16x32_f16(Acur[ks], Bh[ks], ct, 0, 0, 0);
                #pragma unroll
                for (int j = 0; j < 4; ++j)
                    acc0[j] = fmaf(fmaxf(ct[j], 0.0f), pe, acc0[j]);

                #pragma unroll
                for (int ks = 0; ks < KS; ++ks) Acur[ks] = Anxt[ks];
                bias = biasn;
            }
            // sub 1 (rows 16..31 of expert ee) -> acc1 ; prefetch mt=2*(ee+1)
            {
                int een = (ee + 1 < 8) ? ee + 1 : 0;
                const unsigned short* apn = apl + (2 * een) * (KS * 512);
                #pragma unroll
                for (int ks = 0; ks < KS; ++ks)
                    Anxt[ks] = *(const half8*)(apn + ks * 512);
                f32x4 biasn = *(const f32x4*)&sbL[(2 * een) * 16 + row4];
                float pen = __shfl(pev, een);

                f32x4 ct = bias;
                #pragma unroll
                for (int ks = 0; ks < KS; ++ks)
                    ct = __builtin_amdgcn_mfma_f32_16x16x32_f16(Acur[ks], Bh[ks], ct, 0, 0, 0);
                #pragma unroll
                for (int j = 0; j < 4; ++j)
                    acc1[j] = fmaf(fmaxf(ct[j], 0.0f), pe, acc1[j]);

                #pragma unroll
                for (int ks = 0; ks < KS; ++ks) Acur[ks] = Anxt[ks];
                bias = biasn; pe = pen;
            }
        }
    }

    if (!LAST) {
        union { _Float16 h[4]; u16x4 u; } o;
        #pragma unroll
        for (int j = 0; j < 4; ++j) o.h[j] = (_Float16)acc0[j];
        *(u16x4*)(aout + wbase + row4) = o.u;
    } else {
        #pragma unroll
        for (int j = 0; j < 4; ++j) {
            float s0 = acc0[j], s1 = acc1[j];
            #pragma unroll
            for (int off = 1; off < 16; off <<= 1) {
                s0 += __shfl_xor(s0, off);
                s1 += __shfl_xor(s1, off);
            }
            if ((l & 15) == 0) {
                ps[nt][row4 + j] = s0;
                ps[nt][16 + row4 + j] = s1;
            }
        }
    }
}

// ---------------- Fused all-4-layer conv + per-patch channel sums -----------
__global__ __launch_bounds__(256, 4) void pce_fused(
    const float* __restrict__ X,
    const unsigned short* __restrict__ wA0, const unsigned short* __restrict__ wA1,
    const unsigned short* __restrict__ wA2, const unsigned short* __restrict__ wA3,
    const float* __restrict__ eb0, const float* __restrict__ eb1,
    const float* __restrict__ eb2, const float* __restrict__ eb3,
    const float* __restrict__ probs,  // [4][256][8]
    float* __restrict__ psums)        // [16][256][32]
{
    int bx = blockIdx.x;
    int b = bx >> 8, p = bx & 255;
    int py = p >> 4, px = p & 15;
    int tid = threadIdx.x;

    __shared__ alignas(16) unsigned short A0[NELEM];
    __shared__ alignas(16) unsigned short A1[NELEM];
    __shared__ alignas(16) float sb[640];
    __shared__ alignas(16) float se[4][8];
    __shared__ float ps[4][32];

    {
        u32x4 z = {0u, 0u, 0u, 0u};
        for (int t = tid; t < 300; t += 256) {
            ((u32x4*)A0)[t] = z;
            ((u32x4*)A1)[t] = z;
        }
    }
    for (int t = tid; t < 192; t += 256) {
        int cin = t >> 6, pix = t & 63, i = pix >> 3, j = pix & 7;
        float v = X[((size_t)(b * 3 + cin) * 128 + (py * 8 + i)) * 128 + (px * 8 + j)];
        A0[(1 + i) * ROWS + (1 + j) * CP + cin] = f2h_bits(v);
    }
    if (tid < 32) se[tid >> 3][tid & 7] = probs[(tid >> 3) * 2048 + p * 8 + (tid & 7)];
    for (int t = tid; t < 640; t += 256) {
        float v;
        if (t < 128)      { int e = t >> 4, r = t & 15; v = (r < 8) ? eb0[e * 8 + r] : 0.0f; }
        else if (t < 256) v = eb1[t - 128];
        else if (t < 384) v = eb2[t - 256];
        else              v = eb3[t - 384];
        sb[t] = v;
    }
    __syncthreads();

    int l = tid & 63, nt = tid >> 6;
    int n = nt * 16 + (l & 15);
    int pr = n >> 3, pc = n & 7;
    int lane4 = l >> 4, row4 = lane4 * 4;

    layer_run<2, 4, 8, 1, false>(A0, A1, wA0, sb,       se[0], l, lane4, pr, pc, row4, nullptr, nt);
    __syncthreads();
    layer_run<3, 8, 8, 1, false>(A1, A0, wA1, sb + 128, se[1], l, lane4, pr, pc, row4, nullptr, nt);
    __syncthreads();
    layer_run<5, 16, 8, 1, false>(A0, A1, wA2, sb + 256, se[2], l, lane4, pr, pc, row4, nullptr, nt);
    __syncthreads();
    layer_run<5, 16, 16, 2, true>(A1, A0, wA3, sb + 384, se[3], l, lane4, pr, pc, row4, ps, nt);
    __syncthreads();

    if (tid < 32) {
        float s = ps[0][tid] + ps[1][tid] + ps[2][tid] + ps[3][tid];
        psums[(size_t)(b * 256 + p) * 32 + tid] = s;
    }
}

// ---------------- FC: 128 blocks = 16 b x 8 class-chunks --------------------
__global__ __launch_bounds__(256) void fc_kernel(
    const float* __restrict__ psums, const float* __restrict__ fcw,
    const float* __restrict__ fcb, float* __restrict__ out)
{
    int b = blockIdx.x >> 3, chunk = blockIdx.x & 7;
    __shared__ float pooled[2048];
    for (int t = threadIdx.x; t < 2048; t += 256) {
        int c = t >> 6, cell = t & 63, oy = cell >> 3, ox = cell & 7;
        float s = 0.0f;
        #pragma unroll
        for (int dy = 0; dy < 2; ++dy)
            #pragma unroll
            for (int dx = 0; dx < 2; ++dx) {
                int pp = (2 * oy + dy) * 16 + (2 * ox + dx);
                s += psums[(size_t)(b * 256 + pp) * 32 + c];
            }
        pooled[t] = s * (1.0f / 256.0f);
    }
    __syncthreads();

    int wave = threadIdx.x >> 6, lane = threadIdx.x & 63;
    for (int ci = wave; ci < 13; ci += 4) {
        int cls = chunk * 13 + ci;
        if (cls < 100) {
            float a = 0.0f;
            #pragma unroll
            for (int r = 0; r < 32; ++r)
                a += pooled[r * 64 + lane] * fcw[(size_t)cls * 2048 + r * 64 + lane];
            #pragma unroll
            for (int off = 32; off > 0; off >>= 1) a += __shfl_down(a, off);
            if (lane == 0) out[b * 100 + cls] = a + fcb[cls];
        }
    }
}

// ---------------- Launch ----------------------------------------------------
extern "C" void kernel_launch(void* const* d_in, const int* in_sizes, int n_in,
                              void* d_out, int out_size, void* d_ws, size_t ws_size,
                              hipStream_t stream) {
    const float* X = (const float*)d_in[0];
    const float* eb[4];
    SetupArgs sa;
    for (int l = 0; l < 4; ++l) {
        sa.ew[l]  = (const float*)d_in[1 + 6*l + 0];
        eb[l]     = (const float*)d_in[1 + 6*l + 1];
        sa.rw[l]  = (const float*)d_in[1 + 6*l + 2];
        sa.rb[l]  = (const float*)d_in[1 + 6*l + 3];
        sa.rlw[l] = (const float*)d_in[1 + 6*l + 4];
        sa.rlb[l] = (const float*)d_in[1 + 6*l + 5];
    }
    const float* fcw = (const float*)d_in[25];
    const float* fcb = (const float*)d_in[26];

    char* ws = (char*)d_ws;
    float* probs  = (float*)ws;                       // 32 KB
    float* psums  = (float*)(ws + 32768);             // 512 KB
    unsigned short* wA0 = (unsigned short*)(ws + 32768 + 524288);
    unsigned short* wA1 = wA0 + 8192;
    unsigned short* wA2 = wA1 + 12288;
    unsigned short* wA3 = wA2 + 20480;                // + 40960

    sa.probs = probs; sa.w0 = wA0; sa.w1 = wA1; sa.w2 = wA2; sa.w3 = wA3;

    setup_all<<<576, 256, 0, stream>>>(sa);
    pce_fused<<<4096, 256, 0, stream>>>(X, wA0, wA1, wA2, wA3,
                                        eb[0], eb[1], eb[2], eb[3], probs, psums);
    fc_kernel<<<128, 256, 0, stream>>>(psums, fcw, fcb, (float*)d_out);
}

// Round 10
// 79.601 us; speedup vs baseline: 1.9745x; 1.3399x over previous
//
#include <hip/hip_runtime.h>
#include <math.h>

#define NE 8
#define PI_F 3.14159265358979323846f

typedef _Float16 half8 __attribute__((ext_vector_type(8)));
typedef float f32x4 __attribute__((ext_vector_type(4)));
typedef unsigned int uint2v __attribute__((ext_vector_type(2)));
typedef unsigned int u32x4 __attribute__((ext_vector_type(4)));
typedef unsigned short u16x4 __attribute__((ext_vector_type(4)));

// Activation LDS layout: fp16, [y 0..9][x 0..9][c 0..23(pad)], u16 units
#define CP 24
#define ROWS 240        // 10 * CP
#define NELEM 2400      // 10*10*CP u16

__device__ __forceinline__ unsigned short f2h_bits(float v) {
    union { _Float16 h; unsigned short u; } cv;
    cv.h = (_Float16)v;
    return cv.u;
}

// ---------------- Setup: routers (blocks 0..255) + weight prep (256..575) ---
struct SetupArgs {
    const float* rw[4]; const float* rb[4]; const float* rlw[4]; const float* rlb[4];
    const float* ew[4];
    float* probs;
    unsigned short* w0; unsigned short* w1; unsigned short* w2; unsigned short* w3;
};

template<int CIN, int COUT_R, int COUT_P, int CSTR, int KS>
__device__ __forceinline__ void prep_one(
    const float* __restrict__ ew, unsigned short* __restrict__ wA, int idx)
{
    int j    = idx & 7;
    int lane = (idx >> 3) & 63;
    int t2   = idx >> 9;
    int ks   = t2 % KS;
    int mt   = t2 / KS;
    int m    = mt * 16 + (lane & 15);
    int e    = m / COUT_P, row = m % COUT_P;
    int k    = ks * 32 + (lane >> 4) * 8 + j;
    int cin  = k % CSTR, r = k / CSTR;
    float val = 0.0f;
    if (row < COUT_R && cin < CIN && r < 9)
        val = ew[((size_t)(e * COUT_R + row) * CIN + cin) * 9 + r];
    wA[idx] = f2h_bits(val);
}

__global__ __launch_bounds__(256) void setup_all(SetupArgs sa)
{
    int bx = blockIdx.x, tid = threadIdx.x;
    if (bx < 256) {
        int layer = tid >> 6, lane = tid & 63;
        const float* rw  = sa.rw[layer];  const float* rb  = sa.rb[layer];
        const float* rlw = sa.rlw[layer]; const float* rlb = sa.rlb[layer];
        int p = bx, py = p >> 4, px = p & 15;
        int i = lane >> 3, j = lane & 7;
        int y = py * 8 + i, x = px * 8 + j;

        float base0 = (x + 0.5f) / 128.0f;
        float base1 = (y + 0.5f) / 128.0f;
        float base2 = (j + 0.5f) / 8.0f;
        float base3 = (i + 0.5f) / 8.0f;

        float coord[52];
        coord[0] = base0; coord[1] = base1; coord[2] = base2; coord[3] = base3;
        int c = 4;
        #pragma unroll
        for (int f = 0; f < 6; ++f) {
            float w = PI_F * (float)(1 << f);
            coord[c+0] = sinf(w * base0); coord[c+1] = sinf(w * base1);
            coord[c+2] = sinf(w * base2); coord[c+3] = sinf(w * base3);
            coord[c+4] = cosf(w * base0); coord[c+5] = cosf(w * base1);
            coord[c+6] = cosf(w * base2); coord[c+7] = cosf(w * base3);
            c += 8;
        }
        float z[16];
        #pragma unroll
        for (int r = 0; r < 16; ++r) {
            float a = rb[r];
            #pragma unroll
            for (int cc = 0; cc < 52; ++cc) a += rw[r*52 + cc] * coord[cc];
            z[r] = fmaxf(a, 0.0f);
        }
        #pragma unroll
        for (int r = 0; r < 16; ++r) {
            float v = z[r];
            #pragma unroll
            for (int off = 32; off > 0; off >>= 1) v += __shfl_xor(v, off);
            z[r] = v * (1.0f / 64.0f);
        }
        int e = lane & 7;
        float logit = rlb[e];
        #pragma unroll
        for (int r = 0; r < 16; ++r) logit += rlw[e*16 + r] * z[r];
        float m = logit;
        #pragma unroll
        for (int off = 4; off > 0; off >>= 1) m = fmaxf(m, __shfl_xor(m, off));
        float ex = expf(logit - m);
        float s = ex;
        #pragma unroll
        for (int off = 4; off > 0; off >>= 1) s += __shfl_xor(s, off);
        float pr = ex / s;
        pr = (pr >= 0.05f) ? pr : 0.0f;
        float s2 = pr;
        #pragma unroll
        for (int off = 4; off > 0; off >>= 1) s2 += __shfl_xor(s2, off);
        pr = pr / (s2 + 1e-9f);
        if (lane < 8) sa.probs[layer * 2048 + p * 8 + lane] = pr;
    } else {
        int idx = (bx - 256) * 256 + tid;
        if (idx < 8192)       prep_one<3, 8, 16, 4, 2>(sa.ew[0], sa.w0, idx);
        else if (idx < 20480) prep_one<8, 16, 16, 8, 3>(sa.ew[1], sa.w1, idx - 8192);
        else if (idx < 40960) prep_one<16, 16, 16, 16, 5>(sa.ew[2], sa.w2, idx - 20480);
        else if (idx < 81920) prep_one<16, 32, 32, 16, 5>(sa.ew[3], sa.w3, idx - 40960);
    }
}

// ---------------- B-fragment build (per ntile) ------------------------------
template<int KS, int CSTR>
__device__ __forceinline__ void build_B(
    half8* B, const unsigned short* ain, int pr, int pc, int lane4)
{
    const int rbase = pr * ROWS + pc * CP;
    if (CSTR == 16) {
        int cb = (lane4 & 1) * 8;
        int rb = lane4 >> 1;
        #pragma unroll
        for (int ks = 0; ks < KS; ++ks) {
            int r0 = 2 * ks, r1 = 2 * ks + 1;
            int o0 = ((r0 / 3) * 10 + (r0 % 3)) * CP;
            int o1 = ((r1 / 3) * 10 + (r1 % 3)) * CP;
            int off = rb ? o1 : o0;
            half8 v{};
            if (2 * ks + rb < 9) v = *(const half8*)(ain + rbase + off + cb);
            B[ks] = v;
        }
    } else if (CSTR == 8) {
        #pragma unroll
        for (int ks = 0; ks < KS; ++ks) {
            int r = 4 * ks + lane4;
            int dy = (r * 11) >> 5, dx = r - 3 * dy;
            half8 v{};
            if (r < 9) v = *(const half8*)(ain + rbase + (dy * 10 + dx) * CP);
            B[ks] = v;
        }
    } else { // CSTR == 4
        #pragma unroll
        for (int ks = 0; ks < KS; ++ks) {
            union { half8 v; uint2v u2[2]; } bb;
            #pragma unroll
            for (int h = 0; h < 2; ++h) {
                int r = 8 * ks + 2 * lane4 + h;
                int dy = (r * 11) >> 5, dx = r - 3 * dy;
                uint2v u{};
                if (r < 9) u = *(const uint2v*)(ain + rbase + (dy * 10 + dx) * CP);
                bb.u2[h] = u;
            }
            B[ks] = bb.v;
        }
    }
}

// ---------------- One layer: 2 ntiles per wave, copy-free A dbuf ------------
template<int KS, int CSTR, int MT, int MPE, bool LAST>
__device__ __forceinline__ void layer_run2(
    const unsigned short* ain, unsigned short* aout,
    const unsigned short* __restrict__ wA,
    const float* sbL, const float* seL,
    int lane4, int row4,
    int pr0, int pc0, int pr1, int pc1,
    float (*ps)[32], int w, int l)
{
    half8 B0[KS], B1[KS];
    build_B<KS, CSTR>(B0, ain, pr0, pc0, lane4);
    build_B<KS, CSTR>(B1, ain, pr1, pc1, lane4);

    f32x4 acc00 = {0.f,0.f,0.f,0.f};   // ntile0, sub0
    f32x4 acc01 = {0.f,0.f,0.f,0.f};   // ntile0, sub1 (MPE==2)
    f32x4 acc10 = {0.f,0.f,0.f,0.f};   // ntile1, sub0
    f32x4 acc11 = {0.f,0.f,0.f,0.f};   // ntile1, sub1

    const unsigned short* apl = wA + l * 8;
    half8 Aa[KS], Ab[KS];
    #pragma unroll
    for (int ks = 0; ks < KS; ++ks)
        Aa[ks] = *(const half8*)(apl + ks * 512);

    #pragma unroll 1
    for (int mt = 0; mt < MT; mt += 2) {
        // prefetch odd tile into Ab
        #pragma unroll
        for (int ks = 0; ks < KS; ++ks)
            Ab[ks] = *(const half8*)(apl + ((mt + 1) * KS + ks) * 512);

        // compute even tile mt with Aa
        {
            float pe = seL[(MPE == 2) ? (mt >> 1) : mt];
            f32x4 c0 = *(const f32x4*)&sbL[mt * 16 + row4];
            f32x4 c1 = c0;
            #pragma unroll
            for (int ks = 0; ks < KS; ++ks) {
                c0 = __builtin_amdgcn_mfma_f32_16x16x32_f16(Aa[ks], B0[ks], c0, 0, 0, 0);
                c1 = __builtin_amdgcn_mfma_f32_16x16x32_f16(Aa[ks], B1[ks], c1, 0, 0, 0);
            }
            #pragma unroll
            for (int j = 0; j < 4; ++j) {
                acc00[j] = fmaf(fmaxf(c0[j], 0.0f), pe, acc00[j]);
                acc10[j] = fmaf(fmaxf(c1[j], 0.0f), pe, acc10[j]);
            }
        }

        // prefetch next even tile into Aa (clamped; wasted on last iter)
        int mtn = (mt + 2 < MT) ? (mt + 2) : 0;
        #pragma unroll
        for (int ks = 0; ks < KS; ++ks)
            Aa[ks] = *(const half8*)(apl + (mtn * KS + ks) * 512);

        // compute odd tile mt+1 with Ab
        {
            float pe = seL[(MPE == 2) ? (mt >> 1) : (mt + 1)];
            f32x4 c0 = *(const f32x4*)&sbL[(mt + 1) * 16 + row4];
            f32x4 c1 = c0;
            #pragma unroll
            for (int ks = 0; ks < KS; ++ks) {
                c0 = __builtin_amdgcn_mfma_f32_16x16x32_f16(Ab[ks], B0[ks], c0, 0, 0, 0);
                c1 = __builtin_amdgcn_mfma_f32_16x16x32_f16(Ab[ks], B1[ks], c1, 0, 0, 0);
            }
            #pragma unroll
            for (int j = 0; j < 4; ++j) {
                if (MPE == 2) {
                    acc01[j] = fmaf(fmaxf(c0[j], 0.0f), pe, acc01[j]);
                    acc11[j] = fmaf(fmaxf(c1[j], 0.0f), pe, acc11[j]);
                } else {
                    acc00[j] = fmaf(fmaxf(c0[j], 0.0f), pe, acc00[j]);
                    acc10[j] = fmaf(fmaxf(c1[j], 0.0f), pe, acc10[j]);
                }
            }
        }
    }

    if (!LAST) {
        const int wbase0 = (1 + pr0) * ROWS + (1 + pc0) * CP;
        const int wbase1 = (1 + pr1) * ROWS + (1 + pc1) * CP;
        union { _Float16 h[4]; u16x4 u; } o0, o1;
        #pragma unroll
        for (int j = 0; j < 4; ++j) {
            o0.h[j] = (_Float16)acc00[j];
            o1.h[j] = (_Float16)acc10[j];
        }
        *(u16x4*)(aout + wbase0 + row4) = o0.u;
        *(u16x4*)(aout + wbase1 + row4) = o1.u;
    } else {
        #pragma unroll
        for (int j = 0; j < 4; ++j) {
            float s0 = acc00[j] + acc10[j];     // sub0, both ntiles
            float s1 = acc01[j] + acc11[j];     // sub1, both ntiles
            #pragma unroll
            for (int off = 1; off < 16; off <<= 1) {
                s0 += __shfl_xor(s0, off);
                s1 += __shfl_xor(s1, off);
            }
            if ((l & 15) == 0) {
                ps[w][row4 + j] = s0;
                ps[w][16 + row4 + j] = s1;
            }
        }
    }
}

// ---------------- Fused all-4-layer conv, 2 patches per block ---------------
__global__ __launch_bounds__(256, 4) void pce_fused(
    const float* __restrict__ X,
    const unsigned short* __restrict__ wA0, const unsigned short* __restrict__ wA1,
    const unsigned short* __restrict__ wA2, const unsigned short* __restrict__ wA3,
    const float* __restrict__ eb0, const float* __restrict__ eb1,
    const float* __restrict__ eb2, const float* __restrict__ eb3,
    const float* __restrict__ probs,  // [4][256][8]
    float* __restrict__ psums)        // [16][256][32]
{
    int bx = blockIdx.x;              // 0..2047
    int b = bx >> 7;
    int pp = (bx & 127) << 1;         // patch pair base
    int tid = threadIdx.x;

    __shared__ alignas(16) unsigned short A0[2][NELEM];
    __shared__ alignas(16) unsigned short A1[2][NELEM];
    __shared__ alignas(16) float sb[640];
    __shared__ alignas(16) float se[4][2][8];
    __shared__ float ps[4][32];

    {
        u32x4 z = {0u, 0u, 0u, 0u};
        for (int t = tid; t < 600; t += 256) {
            ((u32x4*)A0)[t] = z;
            ((u32x4*)A1)[t] = z;
        }
    }
    if (tid < 64) {
        int layer = tid >> 4, q = (tid >> 3) & 1, e = tid & 7;
        se[layer][q][e] = probs[layer * 2048 + (pp + q) * 8 + e];
    }
    for (int t = tid; t < 640; t += 256) {
        float v;
        if (t < 128)      { int e = t >> 4, r = t & 15; v = (r < 8) ? eb0[e * 8 + r] : 0.0f; }
        else if (t < 256) v = eb1[t - 128];
        else if (t < 384) v = eb2[t - 256];
        else              v = eb3[t - 384];
        sb[t] = v;
    }
    __syncthreads();   // zero-init fully visible before interior staging

    for (int t = tid; t < 384; t += 256) {
        int q = t / 192, r = t - q * 192;
        int cin = r >> 6, pix = r & 63, i = pix >> 3, j = pix & 7;
        int p = pp + q, py = p >> 4, px = p & 15;
        float v = X[((size_t)(b * 3 + cin) * 128 + (py * 8 + i)) * 128 + (px * 8 + j)];
        A0[q][(1 + i) * ROWS + (1 + j) * CP + cin] = f2h_bits(v);
    }
    __syncthreads();

    int l = tid & 63, w = tid >> 6;
    int q = w >> 1;
    int n0 = (w & 1) * 32 + (l & 15), n1 = n0 + 16;
    int pr0 = n0 >> 3, pc0 = n0 & 7;
    int pr1 = n1 >> 3, pc1 = n1 & 7;
    int lane4 = l >> 4, row4 = lane4 * 4;

    layer_run2<2, 4, 8, 1, false>(A0[q], A1[q], wA0, sb,       se[0][q], lane4, row4, pr0, pc0, pr1, pc1, nullptr, w, l);
    __syncthreads();
    layer_run2<3, 8, 8, 1, false>(A1[q], A0[q], wA1, sb + 128, se[1][q], lane4, row4, pr0, pc0, pr1, pc1, nullptr, w, l);
    __syncthreads();
    layer_run2<5, 16, 8, 1, false>(A0[q], A1[q], wA2, sb + 256, se[2][q], lane4, row4, pr0, pc0, pr1, pc1, nullptr, w, l);
    __syncthreads();
    layer_run2<5, 16, 16, 2, true>(A1[q], A0[q], wA3, sb + 384, se[3][q], lane4, row4, pr0, pc0, pr1, pc1, ps, w, l);
    __syncthreads();

    if (tid < 64) {
        int qq = tid >> 5, c = tid & 31;
        psums[(size_t)(b * 256 + pp + qq) * 32 + c] = ps[2 * qq][c] + ps[2 * qq + 1][c];
    }
}

// ---------------- FC: 128 blocks = 16 b x 8 class-chunks --------------------
__global__ __launch_bounds__(256) void fc_kernel(
    const float* __restrict__ psums, const float* __restrict__ fcw,
    const float* __restrict__ fcb, float* __restrict__ out)
{
    int b = blockIdx.x >> 3, chunk = blockIdx.x & 7;
    __shared__ float pooled[2048];
    for (int t = threadIdx.x; t < 2048; t += 256) {
        int c = t >> 6, cell = t & 63, oy = cell >> 3, ox = cell & 7;
        float s = 0.0f;
        #pragma unroll
        for (int dy = 0; dy < 2; ++dy)
            #pragma unroll
            for (int dx = 0; dx < 2; ++dx) {
                int pp = (2 * oy + dy) * 16 + (2 * ox + dx);
                s += psums[(size_t)(b * 256 + pp) * 32 + c];
            }
        pooled[t] = s * (1.0f / 256.0f);
    }
    __syncthreads();

    int wave = threadIdx.x >> 6, lane = threadIdx.x & 63;
    for (int ci = wave; ci < 13; ci += 4) {
        int cls = chunk * 13 + ci;
        if (cls < 100) {
            float a = 0.0f;
            #pragma unroll
            for (int r = 0; r < 32; ++r)
                a += pooled[r * 64 + lane] * fcw[(size_t)cls * 2048 + r * 64 + lane];
            #pragma unroll
            for (int off = 32; off > 0; off >>= 1) a += __shfl_down(a, off);
            if (lane == 0) out[b * 100 + cls] = a + fcb[cls];
        }
    }
}

// ---------------- Launch ----------------------------------------------------
extern "C" void kernel_launch(void* const* d_in, const int* in_sizes, int n_in,
                              void* d_out, int out_size, void* d_ws, size_t ws_size,
                              hipStream_t stream) {
    const float* X = (const float*)d_in[0];
    const float* eb[4];
    SetupArgs sa;
    for (int l = 0; l < 4; ++l) {
        sa.ew[l]  = (const float*)d_in[1 + 6*l + 0];
        eb[l]     = (const float*)d_in[1 + 6*l + 1];
        sa.rw[l]  = (const float*)d_in[1 + 6*l + 2];
        sa.rb[l]  = (const float*)d_in[1 + 6*l + 3];
        sa.rlw[l] = (const float*)d_in[1 + 6*l + 4];
        sa.rlb[l] = (const float*)d_in[1 + 6*l + 5];
    }
    const float* fcw = (const float*)d_in[25];
    const float* fcb = (const float*)d_in[26];

    char* ws = (char*)d_ws;
    float* probs  = (float*)ws;                       // 32 KB
    float* psums  = (float*)(ws + 32768);             // 512 KB
    unsigned short* wA0 = (unsigned short*)(ws + 32768 + 524288);
    unsigned short* wA1 = wA0 + 8192;
    unsigned short* wA2 = wA1 + 12288;
    unsigned short* wA3 = wA2 + 20480;                // + 40960

    sa.probs = probs; sa.w0 = wA0; sa.w1 = wA1; sa.w2 = wA2; sa.w3 = wA3;

    setup_all<<<576, 256, 0, stream>>>(sa);
    pce_fused<<<2048, 256, 0, stream>>>(X, wA0, wA1, wA2, wA3,
                                        eb[0], eb[1], eb[2], eb[3], probs, psums);
    fc_kernel<<<128, 256, 0, stream>>>(psums, fcw, fcb, (float*)d_out);
}